// Round 4
// baseline (690.029 us; speedup 1.0000x reference)
//
#include <hip/hip_runtime.h>

typedef short s16x8 __attribute__((ext_vector_type(8)));   // 8 bf16
typedef float f32x16 __attribute__((ext_vector_type(16))); // 32x32 MFMA acc

#define CODES_ELEMS 8388608   // 16*1024*512
#define N_ROWS      131072    // 16*1024*8
#define IDX_OFF     CODES_ELEMS
#define LOSS_OFF    (CODES_ELEMS + N_ROWS)

// d_ws: [0,4) loss acc; [64,8256) cc[2048];
// [8448,532736) cbs bf16-split tiled codebook [group64][frag8][lane64][8]
//   frag 0-3 = c1 dims 0..63, frag 4-7 = c2 (exact residual) dims 0..63
#define WS_LOSS 0
#define WS_CC   64
#define WS_CBS  8448
// margin: trunc granularity at values ~512-900 is <=0.008; unflagged =>
// true gap >= 0.0625-2*0.008 = 0.046 > reorder threshold 0.008 => argmin exact.
// (validated r13 harness run: absmax 0 with these exact constants.)
#define MARGIN_T 0.0625f
// row-constant positivity offset (validated r13): uint-min == float-min.
#define DIST_OFF 512.0f

__device__ __forceinline__ float bf2f(unsigned short h) { return __uint_as_float(((unsigned)h) << 16); }
__device__ __forceinline__ unsigned short f2bf(float f) {   // RNE
  unsigned u = __float_as_uint(f);
  u += 0x7fffu + ((u >> 16) & 1u);
  return (unsigned short)(u >> 16);
}
// async global->LDS, 16B/lane; dest = wave-uniform base + lane*16
__device__ __forceinline__ void gl_lds16(const void* g, void* l) {
  __builtin_amdgcn_global_load_lds(
      (__attribute__((address_space(1))) void*)(g),
      (__attribute__((address_space(3))) void*)(l), 16, 0, 0);
}

// Prep (validated r13): bf16-split codebook into 32x32x16 B-fragment layout +
// cc[k]=sum c^2 (per-wave butterfly, one code per wave, d=lane).
__global__ __launch_bounds__(256) void vq_prep(const float* __restrict__ cb,
                                               float* __restrict__ cc,
                                               unsigned short* __restrict__ cbs,
                                               float* __restrict__ loss) {
  int t = threadIdx.x;
  if (blockIdx.x == 0 && t == 0) loss[0] = 0.f;
  int e = blockIdx.x * 256 + t;   // 1024*256 = 2048 codes * 128 K-elems
  int k = e >> 7, K = e & 127;
  int limb = K >> 6, d = K & 63;
  float c = cb[k * 64 + d];
  unsigned short c1 = f2bf(c);
  unsigned short val = limb ? f2bf(c - bf2f(c1)) : c1;   // exact residual split
  int group = k >> 5, n = k & 31;
  int f = limb * 4 + (d >> 4);
  int lane = ((d >> 3) & 1) * 32 + n;
  int j = d & 7;
  cbs[(((size_t)group * 8 + f) * 64 + lane) * 8 + j] = val;
  float sq = c * c;
  #pragma unroll
  for (int m = 1; m < 64; m <<= 1) sq += __shfl_xor(sq, m, 64);
  if ((t & 63) == 0) cc[k] = sq;
}

// Mega-kernel r14: 128 rows x 2048 codes per block (grid 1024), 4 waves, ONE
// 32-row tile per wave (r13's two-tile variant spilled ~100 regs -> 1GB scratch
// traffic; halved live set: az 32 + p 32 + bc 32 + acc 16(AGPR) ~= 130 regs).
// Phases identical to r13 (harness-validated, absmax 0): K-loop w/ dbuf
// gl_lds staging -> unpack/merge -> exact fp32 rescore of flagged -> epilogue.
__global__ __launch_bounds__(256, 2) void VQQuantizer_30064771072206_kernel(
    const float* __restrict__ zf, const float* __restrict__ cb,
    const unsigned short* __restrict__ cbs, const float* __restrict__ cc,
    float* __restrict__ loss, float* __restrict__ out)
{
  __shared__ __align__(16) unsigned short bt[2][16384];  // 2 x 32KB: [group4][frag8][lane64][8]
  __shared__ __align__(16) float cc_l[2048];
  // ---- tail arena aliased onto bt (only touched after the K-loop) ----
  int*   idx_l  = (int*)&bt[0][0];                        // 128 ints  [0,512)
  int*   flg    = (int*)((char*)&bt[0][0] + 1024);        // 128 ints  [1024,1536)
  int*   nf     = (int*)((char*)&bt[0][0] + 2048);        // [2048,2052)
  float (*zl)[68] = (float(*)[68])((char*)&bt[0][0] + 2064);  // 8*68 f
  float* zz_l   = (float*)((char*)&bt[0][0] + 4240);      // 8 f
  int*   rows_s = (int*)((char*)&bt[0][0] + 4272);        // 8 i
  float (*rv)[8] = (float(*)[8])((char*)&bt[0][0] + 4304); // 4x8 f
  int   (*ri)[8] = (int(*)[8])((char*)&bt[0][0] + 4432);   // 4x8 i
  float* wsum   = (float*)((char*)&bt[0][0] + 4560);      // 4 f

  const int t = threadIdx.x, w = t >> 6, l = t & 63;
  const int col = l & 31, hi = l >> 5;
  const int R0 = blockIdx.x * 128;
  const float4* zf4 = (const float4*)zf;
  const float4* cb4 = (const float4*)cb;

  // prologue: stage group-chunk 0 (4 groups = 32KB) into buf 0; load cc_l
  #pragma unroll
  for (int i = 0; i < 8; ++i) {
    int s0 = i * 256 + w * 64;            // wave-uniform 16B-slot base
    gl_lds16(cbs + (size_t)(s0 + l) * 8, &bt[0][(size_t)s0 * 8]);
  }
  #pragma unroll
  for (int i = 0; i < 2; ++i)
    ((float4*)cc_l)[i * 256 + t] = ((const float4*)cc)[i * 256 + t];

  // A-frags (32x32x16, validated r13): lane holds A[m=l&31][k=hi*8+j];
  // frag f covers dims f*16 + hi*8 + j. Row = R0 + w*32 + (l&31).
  s16x8 az1[4], az2[4];   // [frag]: bf16(-2z) and exact residual
  {
    int row = R0 + w * 32 + col;
    const float4* zr = zf4 + (size_t)row * 16;
    #pragma unroll
    for (int f = 0; f < 4; ++f) {
      float4 u0 = zr[f * 4 + hi * 2];
      float4 u1 = zr[f * 4 + hi * 2 + 1];
      float m2[8] = {-2.f*u0.x, -2.f*u0.y, -2.f*u0.z, -2.f*u0.w,
                     -2.f*u1.x, -2.f*u1.y, -2.f*u1.z, -2.f*u1.w};
      #pragma unroll
      for (int j = 0; j < 8; ++j) {
        unsigned short h1 = f2bf(m2[j]);
        unsigned short h2 = f2bf(m2[j] - bf2f(h1));
        az1[f][j] = (short)h1;
        az2[f][j] = (short)h2;
      }
    }
  }

  unsigned p1[16], p2[16];   // packed (trunc dist | group-pid): best/second
  #pragma unroll
  for (int r = 0; r < 16; ++r) { p1[r] = 0xFFFFFFFFu; p2[r] = 0xFFFFFFFFu; }

  __syncthreads();   // drains prologue stage + cc_l

  int cur = 0;
  for (int chunk = 0; chunk < 16; ++chunk) {
    if (chunk + 1 < 16) {            // prefetch next 4 groups into buf^1
      const unsigned short* src = cbs + (size_t)(chunk + 1) * 16384;
      unsigned short* dst = &bt[cur ^ 1][0];
      #pragma unroll
      for (int i = 0; i < 8; ++i) {
        int s0 = i * 256 + w * 64;
        gl_lds16(src + (size_t)(s0 + l) * 8, dst + (size_t)s0 * 8);
      }
    }
    #pragma unroll
    for (int g = 0; g < 4; ++g) {
      int group = chunk * 4 + g;
      float nh = DIST_OFF + cc_l[group * 32 + col];
      const unsigned short* base = &bt[cur][((size_t)g * 8 * 64 + l) * 8];
      s16x8 bc0 = *(const s16x8*)(base + 0 * 512);   // c1 frags
      s16x8 bc1 = *(const s16x8*)(base + 1 * 512);
      s16x8 bc2 = *(const s16x8*)(base + 2 * 512);
      s16x8 bc3 = *(const s16x8*)(base + 3 * 512);
      s16x8 bc4 = *(const s16x8*)(base + 4 * 512);   // c2 frags
      s16x8 bc5 = *(const s16x8*)(base + 5 * 512);
      s16x8 bc6 = *(const s16x8*)(base + 6 * 512);
      s16x8 bc7 = *(const s16x8*)(base + 7 * 512);
      unsigned pid = (unsigned)group;                // 6 bits, ascending codes
      f32x16 acc;
      #pragma unroll
      for (int r = 0; r < 16; ++r) acc[r] = nh;
      acc = __builtin_amdgcn_mfma_f32_32x32x16_bf16(az1[0], bc0, acc, 0, 0, 0);
      acc = __builtin_amdgcn_mfma_f32_32x32x16_bf16(az1[1], bc1, acc, 0, 0, 0);
      acc = __builtin_amdgcn_mfma_f32_32x32x16_bf16(az1[2], bc2, acc, 0, 0, 0);
      acc = __builtin_amdgcn_mfma_f32_32x32x16_bf16(az1[3], bc3, acc, 0, 0, 0);
      acc = __builtin_amdgcn_mfma_f32_32x32x16_bf16(az2[0], bc0, acc, 0, 0, 0);
      acc = __builtin_amdgcn_mfma_f32_32x32x16_bf16(az2[1], bc1, acc, 0, 0, 0);
      acc = __builtin_amdgcn_mfma_f32_32x32x16_bf16(az2[2], bc2, acc, 0, 0, 0);
      acc = __builtin_amdgcn_mfma_f32_32x32x16_bf16(az2[3], bc3, acc, 0, 0, 0);
      acc = __builtin_amdgcn_mfma_f32_32x32x16_bf16(az1[0], bc4, acc, 0, 0, 0);
      acc = __builtin_amdgcn_mfma_f32_32x32x16_bf16(az1[1], bc5, acc, 0, 0, 0);
      acc = __builtin_amdgcn_mfma_f32_32x32x16_bf16(az1[2], bc6, acc, 0, 0, 0);
      acc = __builtin_amdgcn_mfma_f32_32x32x16_bf16(az1[3], bc7, acc, 0, 0, 0);
      #pragma unroll
      for (int r = 0; r < 16; ++r) {   // packed (best, second): 4 int ops
        unsigned pd = (__float_as_uint(acc[r]) & 0xFFFFFF80u) | pid;
        unsigned mx = p1[r] > pd ? p1[r] : pd;
        p2[r] = p2[r] < mx ? p2[r] : mx;
        p1[r] = p1[r] < pd ? p1[r] : pd;
      }
    }
    __syncthreads();   // readers done with cur; prefetch landed in cur^1
    cur ^= 1;
  }

  // ---- phase 2: unpack + merge across the 32 lanes of each half ----
  if (t == 0) *nf = 0;
  __syncthreads();     // bt dead; arena live from here
  #pragma unroll
  for (int r = 0; r < 16; ++r) {
    float a   = __uint_as_float(p1[r] & 0xFFFFFF80u);
    int   ia  = (int)(p1[r] & 127u) * 32 + col;   // code = pid*32+col
    float b2v = __uint_as_float(p2[r] & 0xFFFFFF80u);
    #pragma unroll
    for (int m = 1; m < 32; m <<= 1) {   // halves hold different rows
      float oa = __shfl_xor(a, m, 64);
      int   oi = __shfl_xor(ia, m, 64);
      float ob = __shfl_xor(b2v, m, 64);
      float hv = fmaxf(a, oa);
      b2v = fminf(fminf(b2v, ob), hv);
      bool take = (oa < a) || (oa == a && oi < ia);
      a = take ? oa : a; ia = take ? oi : ia;
    }
    if (col == 0) {  // C/D: col=l&31, row=(r&3)+8*(r>>2)+4*(l>>5) [m74/m101]
      int rl = w * 32 + 4 * hi + (r & 3) + 8 * (r >> 2);
      idx_l[rl] = ia;
      if (b2v - a < MARGIN_T) {
        int p = atomicAdd(nf, 1);
        flg[p] = rl;
      }
    }
  }
  __syncthreads();

  // ---- phase 3: exact fp32 rescore of flagged rows (validated inner chain) ----
  int count = *nf;
  for (int itb = 0; itb * 8 < count; ++itb) {
    if (itb) __syncthreads();
    if (t < 8) {
      int ii = itb * 8 + t;
      rows_s[t] = flg[ii < count ? ii : count - 1];  // tail dup: benign rewrite
    }
    __syncthreads();
    if (t < 128) {
      int r = t >> 4, dq = t & 15;
      *(float4*)&zl[r][dq * 4] = zf4[(size_t)(R0 + rows_s[r]) * 16 + dq];
    }
    __syncthreads();
    if (t < 8) {                          // zz: sequential-d np chain
      float s = 0.f;
      for (int d = 0; d < 64; ++d) { float v = zl[t][d]; s += v * v; }
      zz_l[t] = s;
    }
    __syncthreads();

    float bv[8]; int bi[8];
    #pragma unroll
    for (int r = 0; r < 8; ++r) { bv[r] = 3.402823466e38f; bi[r] = 0; }
    #pragma unroll 1
    for (int o = 0; o < 8; ++o) {         // thread's codes ascending: o*256+t
      int c = o * 256 + t;
      const float4* cr = cb4 + (size_t)c * 16;
      float a[8];
      #pragma unroll
      for (int r = 0; r < 8; ++r) a[r] = 0.f;
      #pragma unroll
      for (int dq = 0; dq < 16; ++dq) {
        float4 cv = cr[dq];
        #pragma unroll
        for (int r = 0; r < 8; ++r) {
          float4 z4 = *(const float4*)&zl[r][dq * 4];
          a[r] += z4.x * cv.x;
          a[r] += z4.y * cv.y;
          a[r] += z4.z * cv.z;
          a[r] += z4.w * cv.w;
        }
      }
      float ccv = cc_l[c];
      #pragma unroll
      for (int r = 0; r < 8; ++r) {
        float t0 = zz_l[r] - 2.0f * a[r];
        float dist = t0 + ccv;
        if (dist < bv[r]) { bv[r] = dist; bi[r] = c; }
      }
    }
    #pragma unroll
    for (int r = 0; r < 8; ++r) {
      float v = bv[r]; int idx = bi[r];
      #pragma unroll
      for (int m = 1; m < 64; m <<= 1) {
        float ov = __shfl_xor(v, m, 64); int oi = __shfl_xor(idx, m, 64);
        if (ov < v || (ov == v && oi < idx)) { v = ov; idx = oi; }
      }
      if (l == 0) { rv[w][r] = v; ri[w][r] = idx; }
    }
    __syncthreads();
    if (t < 8) {
      float fv = rv[0][t]; int fi = ri[0][t];
      #pragma unroll
      for (int k = 1; k < 4; ++k) {
        if (rv[k][t] < fv || (rv[k][t] == fv && ri[k][t] < fi)) { fv = rv[k][t]; fi = ri[k][t]; }
      }
      idx_l[rows_s[t]] = fi;
    }
  }
  __syncthreads();

  // ---- phase 4: epilogue for this block's 128 rows ----
  float4* out4 = (float4*)out;
  float lsum = 0.f;
  #pragma unroll
  for (int i = 0; i < 8; ++i) {
    int f = i * 256 + t;
    int row = f >> 4, dq = f & 15;
    int k = idx_l[row];
    float4 qv = cb4[(size_t)k * 16 + dq];
    float4 zv = zf4[(size_t)(R0 + row) * 16 + dq];
    float dx = qv.x - zv.x, dy = qv.y - zv.y, dz = qv.z - zv.z, dw = qv.w - zv.w;
    float4 st; st.x = zv.x + dx; st.y = zv.y + dy; st.z = zv.z + dz; st.w = zv.w + dw;
    out4[(size_t)(R0 + row) * 16 + dq] = st;
    lsum += dx * dx; lsum += dy * dy; lsum += dz * dz; lsum += dw * dw;
  }
  if (t < 128) out[IDX_OFF + R0 + t] = (float)idx_l[t];
  #pragma unroll
  for (int m = 1; m < 64; m <<= 1) lsum += __shfl_xor(lsum, m, 64);
  if (l == 0) wsum[w] = lsum;
  __syncthreads();
  if (t == 0) atomicAdd(loss, wsum[0] + wsum[1] + wsum[2] + wsum[3]);
}

__global__ void vq_finalize(const float* __restrict__ loss, float* __restrict__ out) {
  out[LOSS_OFF] = loss[0] * (1.f / 8388608.f);
}

extern "C" void kernel_launch(void* const* d_in, const int* in_sizes, int n_in,
                              void* d_out, int out_size, void* d_ws, size_t ws_size,
                              hipStream_t stream) {
  const float* z  = (const float*)d_in[0];
  const float* cb = (const float*)d_in[1];
  float* out = (float*)d_out;
  float* loss = (float*)((char*)d_ws + WS_LOSS);
  float* cc   = (float*)((char*)d_ws + WS_CC);
  unsigned short* cbs = (unsigned short*)((char*)d_ws + WS_CBS);

  vq_prep<<<1024, 256, 0, stream>>>(cb, cc, cbs, loss);
  VQQuantizer_30064771072206_kernel<<<1024, 256, 0, stream>>>(z, cb, cbs, cc, loss, out);
  vq_finalize<<<1, 1, 0, stream>>>(loss, out);
}

// Round 5
// 522.109 us; speedup vs baseline: 1.3216x; 1.3216x over previous
//
#include <hip/hip_runtime.h>

typedef short s16x8 __attribute__((ext_vector_type(8)));   // 8 bf16
typedef float f32x16 __attribute__((ext_vector_type(16))); // 32x32 MFMA acc

#define CODES_ELEMS 8388608   // 16*1024*512
#define N_ROWS      131072    // 16*1024*8
#define IDX_OFF     CODES_ELEMS
#define LOSS_OFF    (CODES_ELEMS + N_ROWS)

// d_ws: [0,4) loss acc; [64,8256) cc[2048];
// [8448,532736) cbs bf16-split tiled codebook [group64][frag8][lane64][8]
//   frag 0-3 = c1 dims 0..63, frag 4-7 = c2 (exact residual) dims 0..63
#define WS_LOSS 0
#define WS_CC   64
#define WS_CBS  8448
// margin/packing constants validated r13+r14 (absmax 0 both):
#define MARGIN_T 0.0625f
#define DIST_OFF 512.0f

__device__ __forceinline__ float bf2f(unsigned short h) { return __uint_as_float(((unsigned)h) << 16); }
__device__ __forceinline__ unsigned short f2bf(float f) {   // RNE
  unsigned u = __float_as_uint(f);
  u += 0x7fffu + ((u >> 16) & 1u);
  return (unsigned short)(u >> 16);
}
// async global->LDS, 16B/lane; dest = wave-uniform base + lane*16
__device__ __forceinline__ void gl_lds16(const void* g, void* l) {
  __builtin_amdgcn_global_load_lds(
      (__attribute__((address_space(1))) void*)(g),
      (__attribute__((address_space(3))) void*)(l), 16, 0, 0);
}

// Prep (validated r13/r14): bf16-split codebook into 32x32x16 B-fragment
// layout + cc[k]=sum c^2 (per-wave butterfly, one code per wave, d=lane).
__global__ __launch_bounds__(256) void vq_prep(const float* __restrict__ cb,
                                               float* __restrict__ cc,
                                               unsigned short* __restrict__ cbs,
                                               float* __restrict__ loss) {
  int t = threadIdx.x;
  if (blockIdx.x == 0 && t == 0) loss[0] = 0.f;
  int e = blockIdx.x * 256 + t;   // 1024*256 = 2048 codes * 128 K-elems
  int k = e >> 7, K = e & 127;
  int limb = K >> 6, d = K & 63;
  float c = cb[k * 64 + d];
  unsigned short c1 = f2bf(c);
  unsigned short val = limb ? f2bf(c - bf2f(c1)) : c1;   // exact residual split
  int group = k >> 5, n = k & 31;
  int f = limb * 4 + (d >> 4);
  int lane = ((d >> 3) & 1) * 32 + n;
  int j = d & 7;
  cbs[(((size_t)group * 8 + f) * 64 + lane) * 8 + j] = val;
  float sq = c * c;
  #pragma unroll
  for (int m = 1; m < 64; m <<= 1) sq += __shfl_xor(sq, m, 64);
  if ((t & 63) == 0) cc[k] = sq;
}

// Mega-kernel r15: same validated math/phases as r14 (absmax 0), codegen
// restructured to kill the scratch spill seen in r13/r14 (FETCH ~1GB):
//  - no min-waves launch hint (r13/r14's (256,2) pinned a 128-VGPR budget)
//  - #pragma unroll 1 group loop; B-frags in two 4-reg sets (<=8 live)
//  - chunk = 2 groups: LDS 2x16KB + 8KB cc = 40.2KB -> 3 blocks/CU possible
__global__ __launch_bounds__(256) void VQQuantizer_30064771072206_kernel(
    const float* __restrict__ zf, const float* __restrict__ cb,
    const unsigned short* __restrict__ cbs, const float* __restrict__ cc,
    float* __restrict__ loss, float* __restrict__ out)
{
  __shared__ __align__(16) unsigned short bt[2][8192];   // 2 x 16KB: [group2][frag8][lane64][8]
  __shared__ __align__(16) float cc_l[2048];
  // ---- tail arena aliased onto bt (only touched after the K-loop) ----
  int*   idx_l  = (int*)&bt[0][0];                        // 128 ints  [0,512)
  int*   flg    = (int*)((char*)&bt[0][0] + 1024);        // 128 ints  [1024,1536)
  int*   nf     = (int*)((char*)&bt[0][0] + 2048);        // [2048,2052)
  float (*zl)[68] = (float(*)[68])((char*)&bt[0][0] + 2064);  // 8*68 f
  float* zz_l   = (float*)((char*)&bt[0][0] + 4240);      // 8 f
  int*   rows_s = (int*)((char*)&bt[0][0] + 4272);        // 8 i
  float (*rv)[8] = (float(*)[8])((char*)&bt[0][0] + 4304); // 4x8 f
  int   (*ri)[8] = (int(*)[8])((char*)&bt[0][0] + 4432);   // 4x8 i
  float* wsum   = (float*)((char*)&bt[0][0] + 4560);      // 4 f

  const int t = threadIdx.x, w = t >> 6, l = t & 63;
  const int col = l & 31, hi = l >> 5;
  const int R0 = blockIdx.x * 128;
  const float4* zf4 = (const float4*)zf;
  const float4* cb4 = (const float4*)cb;

  // prologue: stage chunk 0 (2 groups = 16KB) into buf 0; load cc_l
  #pragma unroll
  for (int i = 0; i < 4; ++i) {
    int s0 = i * 256 + w * 64;            // wave-uniform 16B-slot base
    gl_lds16(cbs + (size_t)(s0 + l) * 8, &bt[0][(size_t)s0 * 8]);
  }
  #pragma unroll
  for (int i = 0; i < 2; ++i)
    ((float4*)cc_l)[i * 256 + t] = ((const float4*)cc)[i * 256 + t];

  // A-frags (32x32x16, validated): lane holds A[m=l&31][k=hi*8+j];
  // frag f covers dims f*16 + hi*8 + j. Row = R0 + w*32 + (l&31).
  s16x8 az1[4], az2[4];   // [frag]: bf16(-2z) and exact residual
  {
    int row = R0 + w * 32 + col;
    const float4* zr = zf4 + (size_t)row * 16;
    #pragma unroll
    for (int f = 0; f < 4; ++f) {
      float4 u0 = zr[f * 4 + hi * 2];
      float4 u1 = zr[f * 4 + hi * 2 + 1];
      float m2[8] = {-2.f*u0.x, -2.f*u0.y, -2.f*u0.z, -2.f*u0.w,
                     -2.f*u1.x, -2.f*u1.y, -2.f*u1.z, -2.f*u1.w};
      #pragma unroll
      for (int j = 0; j < 8; ++j) {
        unsigned short h1 = f2bf(m2[j]);
        unsigned short h2 = f2bf(m2[j] - bf2f(h1));
        az1[f][j] = (short)h1;
        az2[f][j] = (short)h2;
      }
    }
  }

  unsigned p1[16], p2[16];   // packed (trunc dist | group-pid): best/second
  #pragma unroll
  for (int r = 0; r < 16; ++r) { p1[r] = 0xFFFFFFFFu; p2[r] = 0xFFFFFFFFu; }

  __syncthreads();   // drains prologue stage + cc_l

  int cur = 0;
  for (int chunk = 0; chunk < 32; ++chunk) {
    if (chunk + 1 < 32) {            // prefetch next 2 groups into buf^1
      const unsigned short* src = cbs + (size_t)(chunk + 1) * 8192;
      unsigned short* dst = &bt[cur ^ 1][0];
      #pragma unroll
      for (int i = 0; i < 4; ++i) {
        int s0 = i * 256 + w * 64;
        gl_lds16(src + (size_t)(s0 + l) * 8, dst + (size_t)s0 * 8);
      }
    }
    #pragma unroll 1                 // fence: one group's frags live at a time
    for (int g = 0; g < 2; ++g) {
      int group = chunk * 2 + g;
      float nh = DIST_OFF + cc_l[group * 32 + col];
      const unsigned short* base = &bt[cur][((size_t)g * 8 * 64 + l) * 8];
      unsigned pid = (unsigned)group;                // 6 bits, ascending codes
      f32x16 acc;
      #pragma unroll
      for (int r = 0; r < 16; ++r) acc[r] = nh;
      {
        s16x8 bcA0 = *(const s16x8*)(base + 0 * 512);   // c1 frags
        s16x8 bcA1 = *(const s16x8*)(base + 1 * 512);
        s16x8 bcA2 = *(const s16x8*)(base + 2 * 512);
        s16x8 bcA3 = *(const s16x8*)(base + 3 * 512);
        acc = __builtin_amdgcn_mfma_f32_32x32x16_bf16(az1[0], bcA0, acc, 0, 0, 0);
        acc = __builtin_amdgcn_mfma_f32_32x32x16_bf16(az1[1], bcA1, acc, 0, 0, 0);
        acc = __builtin_amdgcn_mfma_f32_32x32x16_bf16(az1[2], bcA2, acc, 0, 0, 0);
        acc = __builtin_amdgcn_mfma_f32_32x32x16_bf16(az1[3], bcA3, acc, 0, 0, 0);
        acc = __builtin_amdgcn_mfma_f32_32x32x16_bf16(az2[0], bcA0, acc, 0, 0, 0);
        acc = __builtin_amdgcn_mfma_f32_32x32x16_bf16(az2[1], bcA1, acc, 0, 0, 0);
        acc = __builtin_amdgcn_mfma_f32_32x32x16_bf16(az2[2], bcA2, acc, 0, 0, 0);
        acc = __builtin_amdgcn_mfma_f32_32x32x16_bf16(az2[3], bcA3, acc, 0, 0, 0);
      }
      {
        s16x8 bcB0 = *(const s16x8*)(base + 4 * 512);   // c2 frags
        s16x8 bcB1 = *(const s16x8*)(base + 5 * 512);
        s16x8 bcB2 = *(const s16x8*)(base + 6 * 512);
        s16x8 bcB3 = *(const s16x8*)(base + 7 * 512);
        acc = __builtin_amdgcn_mfma_f32_32x32x16_bf16(az1[0], bcB0, acc, 0, 0, 0);
        acc = __builtin_amdgcn_mfma_f32_32x32x16_bf16(az1[1], bcB1, acc, 0, 0, 0);
        acc = __builtin_amdgcn_mfma_f32_32x32x16_bf16(az1[2], bcB2, acc, 0, 0, 0);
        acc = __builtin_amdgcn_mfma_f32_32x32x16_bf16(az1[3], bcB3, acc, 0, 0, 0);
      }
      #pragma unroll
      for (int r = 0; r < 16; ++r) {   // packed (best, second): ~4 int ops
        unsigned pd = (__float_as_uint(acc[r]) & 0xFFFFFF80u) | pid;
        unsigned mx = p1[r] > pd ? p1[r] : pd;
        p2[r] = p2[r] < mx ? p2[r] : mx;
        p1[r] = p1[r] < pd ? p1[r] : pd;
      }
    }
    __syncthreads();   // readers done with cur; prefetch landed in cur^1
    cur ^= 1;
  }

  // ---- phase 2: unpack + merge across the 32 lanes of each half ----
  if (t == 0) *nf = 0;
  __syncthreads();     // bt dead; arena live from here
  #pragma unroll
  for (int r = 0; r < 16; ++r) {
    float a   = __uint_as_float(p1[r] & 0xFFFFFF80u);
    int   ia  = (int)(p1[r] & 127u) * 32 + col;   // code = pid*32+col
    float b2v = __uint_as_float(p2[r] & 0xFFFFFF80u);
    #pragma unroll
    for (int m = 1; m < 32; m <<= 1) {   // halves hold different rows
      float oa = __shfl_xor(a, m, 64);
      int   oi = __shfl_xor(ia, m, 64);
      float ob = __shfl_xor(b2v, m, 64);
      float hv = fmaxf(a, oa);
      b2v = fminf(fminf(b2v, ob), hv);
      bool take = (oa < a) || (oa == a && oi < ia);
      a = take ? oa : a; ia = take ? oi : ia;
    }
    if (col == 0) {  // C/D: col=l&31, row=(r&3)+8*(r>>2)+4*(l>>5) [m74/m101]
      int rl = w * 32 + 4 * hi + (r & 3) + 8 * (r >> 2);
      idx_l[rl] = ia;
      if (b2v - a < MARGIN_T) {
        int p = atomicAdd(nf, 1);
        flg[p] = rl;
      }
    }
  }
  __syncthreads();

  // ---- phase 3: exact fp32 rescore of flagged rows (validated inner chain) ----
  int count = *nf;
  for (int itb = 0; itb * 8 < count; ++itb) {
    if (itb) __syncthreads();
    if (t < 8) {
      int ii = itb * 8 + t;
      rows_s[t] = flg[ii < count ? ii : count - 1];  // tail dup: benign rewrite
    }
    __syncthreads();
    if (t < 128) {
      int r = t >> 4, dq = t & 15;
      *(float4*)&zl[r][dq * 4] = zf4[(size_t)(R0 + rows_s[r]) * 16 + dq];
    }
    __syncthreads();
    if (t < 8) {                          // zz: sequential-d np chain
      float s = 0.f;
      for (int d = 0; d < 64; ++d) { float v = zl[t][d]; s += v * v; }
      zz_l[t] = s;
    }
    __syncthreads();

    float bv[8]; int bi[8];
    #pragma unroll
    for (int r = 0; r < 8; ++r) { bv[r] = 3.402823466e38f; bi[r] = 0; }
    #pragma unroll 1
    for (int o = 0; o < 8; ++o) {         // thread's codes ascending: o*256+t
      int c = o * 256 + t;
      const float4* cr = cb4 + (size_t)c * 16;
      float a[8];
      #pragma unroll
      for (int r = 0; r < 8; ++r) a[r] = 0.f;
      #pragma unroll
      for (int dq = 0; dq < 16; ++dq) {
        float4 cv = cr[dq];
        #pragma unroll
        for (int r = 0; r < 8; ++r) {
          float4 z4 = *(const float4*)&zl[r][dq * 4];
          a[r] += z4.x * cv.x;
          a[r] += z4.y * cv.y;
          a[r] += z4.z * cv.z;
          a[r] += z4.w * cv.w;
        }
      }
      float ccv = cc_l[c];
      #pragma unroll
      for (int r = 0; r < 8; ++r) {
        float t0 = zz_l[r] - 2.0f * a[r];
        float dist = t0 + ccv;
        if (dist < bv[r]) { bv[r] = dist; bi[r] = c; }
      }
    }
    #pragma unroll
    for (int r = 0; r < 8; ++r) {
      float v = bv[r]; int idx = bi[r];
      #pragma unroll
      for (int m = 1; m < 64; m <<= 1) {
        float ov = __shfl_xor(v, m, 64); int oi = __shfl_xor(idx, m, 64);
        if (ov < v || (ov == v && oi < idx)) { v = ov; idx = oi; }
      }
      if (l == 0) { rv[w][r] = v; ri[w][r] = idx; }
    }
    __syncthreads();
    if (t < 8) {
      float fv = rv[0][t]; int fi = ri[0][t];
      #pragma unroll
      for (int k = 1; k < 4; ++k) {
        if (rv[k][t] < fv || (rv[k][t] == fv && ri[k][t] < fi)) { fv = rv[k][t]; fi = ri[k][t]; }
      }
      idx_l[rows_s[t]] = fi;
    }
  }
  __syncthreads();

  // ---- phase 4: epilogue for this block's 128 rows ----
  float4* out4 = (float4*)out;
  float lsum = 0.f;
  #pragma unroll
  for (int i = 0; i < 8; ++i) {
    int f = i * 256 + t;
    int row = f >> 4, dq = f & 15;
    int k = idx_l[row];
    float4 qv = cb4[(size_t)k * 16 + dq];
    float4 zv = zf4[(size_t)(R0 + row) * 16 + dq];
    float dx = qv.x - zv.x, dy = qv.y - zv.y, dz = qv.z - zv.z, dw = qv.w - zv.w;
    float4 st; st.x = zv.x + dx; st.y = zv.y + dy; st.z = zv.z + dz; st.w = zv.w + dw;
    out4[(size_t)(R0 + row) * 16 + dq] = st;
    lsum += dx * dx; lsum += dy * dy; lsum += dz * dz; lsum += dw * dw;
  }
  if (t < 128) out[IDX_OFF + R0 + t] = (float)idx_l[t];
  #pragma unroll
  for (int m = 1; m < 64; m <<= 1) lsum += __shfl_xor(lsum, m, 64);
  if (l == 0) wsum[w] = lsum;
  __syncthreads();
  if (t == 0) atomicAdd(loss, wsum[0] + wsum[1] + wsum[2] + wsum[3]);
}

__global__ void vq_finalize(const float* __restrict__ loss, float* __restrict__ out) {
  out[LOSS_OFF] = loss[0] * (1.f / 8388608.f);
}

extern "C" void kernel_launch(void* const* d_in, const int* in_sizes, int n_in,
                              void* d_out, int out_size, void* d_ws, size_t ws_size,
                              hipStream_t stream) {
  const float* z  = (const float*)d_in[0];
  const float* cb = (const float*)d_in[1];
  float* out = (float*)d_out;
  float* loss = (float*)((char*)d_ws + WS_LOSS);
  float* cc   = (float*)((char*)d_ws + WS_CC);
  unsigned short* cbs = (unsigned short*)((char*)d_ws + WS_CBS);

  vq_prep<<<1024, 256, 0, stream>>>(cb, cc, cbs, loss);
  VQQuantizer_30064771072206_kernel<<<1024, 256, 0, stream>>>(z, cb, cbs, cc, loss, out);
  vq_finalize<<<1, 1, 0, stream>>>(loss, out);
}

// Round 6
// 386.200 us; speedup vs baseline: 1.7867x; 1.3519x over previous
//
#include <hip/hip_runtime.h>

typedef short s16x8 __attribute__((ext_vector_type(8)));  // 8 bf16
typedef float f32x4 __attribute__((ext_vector_type(4)));  // 16x16 MFMA acc

#define CODES_ELEMS 8388608   // 16*1024*512
#define N_ROWS      131072    // 16*1024*8
#define IDX_OFF     CODES_ELEMS
#define LOSS_OFF    (CODES_ELEMS + N_ROWS)

// d_ws: [0,4) loss acc; [64,8256) cc[2048];
// [8448,532736) cbs bf16-split tiled codebook [chunk32][seg4][ct4][lane64][8]
//   seg 0,1 = c1 dims 0-31/32-63; seg 2,3 = c2 exact residual dims 0-31/32-63
#define WS_LOSS 0
#define WS_CC   64
#define WS_CBS  8448
// validated r13/r14/r15 (absmax 0 x3): packed-min + margin + offset constants
#define MARGIN_T 0.0625f
#define DIST_OFF 512.0f

__device__ __forceinline__ float bf2f(unsigned short h) { return __uint_as_float(((unsigned)h) << 16); }
__device__ __forceinline__ unsigned short f2bf(float f) {   // RNE
  unsigned u = __float_as_uint(f);
  u += 0x7fffu + ((u >> 16) & 1u);
  return (unsigned short)(u >> 16);
}
// async global->LDS, 16B/lane; dest = wave-uniform base + lane*16
__device__ __forceinline__ void gl_lds16(const void* g, void* l) {
  __builtin_amdgcn_global_load_lds(
      (__attribute__((address_space(1))) void*)(g),
      (__attribute__((address_space(3))) void*)(l), 16, 0, 0);
}

// Prep: bf16-split codebook into 16x16x32 B-fragment layout (r12-validated
// math, chunk now 64 codes / ct-width 4) + cc[k] butterfly (validated).
__global__ __launch_bounds__(256) void vq_prep(const float* __restrict__ cb,
                                               float* __restrict__ cc,
                                               unsigned short* __restrict__ cbs,
                                               float* __restrict__ loss) {
  int t = threadIdx.x;
  if (blockIdx.x == 0 && t == 0) loss[0] = 0.f;
  int e = blockIdx.x * 256 + t;   // 1024*256 = 2048 codes * 128 K-elems
  int k = e >> 7, K = e & 127;
  int s = K >> 5, rem = K & 31, q = rem >> 3, j = rem & 7;
  int d = (s < 2) ? K : (K - 64);
  float c = cb[k * 64 + d];
  unsigned short c1 = f2bf(c);
  unsigned short val = (s < 2) ? c1 : f2bf(c - bf2f(c1));  // exact residual split
  int chunk = k >> 6, ct = (k >> 4) & 3, n = k & 15;
  cbs[(((size_t)(chunk * 4 + s) * 4 + ct) * 64 + (q * 16 + n)) * 8 + j] = val;
  float sq = c * c;
  #pragma unroll
  for (int m = 1; m < 64; m <<= 1) sq += __shfl_xor(sq, m, 64);
  if ((t & 63) == 0) cc[k] = sq;
}

// Mega-kernel r16: K-loop = r12's proven 16x16x32 structure (VGPR 100, no
// spill, 282us-total run) with packed-min tracking (validated r13-r15) and
// 16KB chunks (LDS 41KB -> 3 blocks/CU). Tail phases 2-4 fused (validated
// r13-r15): block-local flag list -> exact fp32 rescore -> epilogue.
__global__ __launch_bounds__(256) void VQQuantizer_30064771072206_kernel(
    const float* __restrict__ zf, const float* __restrict__ cb,
    const unsigned short* __restrict__ cbs, const float* __restrict__ cc,
    float* __restrict__ loss, float* __restrict__ out)
{
  __shared__ __align__(16) unsigned short bt[2][8192];   // 2 x 16KB: [seg4][ct4][lane64][8]
  __shared__ __align__(16) float cc_l[2048];
  // ---- tail arena aliased onto bt (only touched after the K-loop) ----
  int*   idx_l  = (int*)&bt[0][0];                        // 256 ints  [0,1024)
  int*   flg    = (int*)((char*)&bt[0][0] + 1024);        // 256 ints  [1024,2048)
  int*   nf     = (int*)((char*)&bt[0][0] + 2048);        // [2048,2052)
  float (*zl)[68] = (float(*)[68])((char*)&bt[0][0] + 2064);  // 8*68 f
  float* zz_l   = (float*)((char*)&bt[0][0] + 4240);      // 8 f
  int*   rows_s = (int*)((char*)&bt[0][0] + 4272);        // 8 i
  float (*rv)[8] = (float(*)[8])((char*)&bt[0][0] + 4304); // 4x8 f
  int   (*ri)[8] = (int(*)[8])((char*)&bt[0][0] + 4432);   // 4x8 i
  float* wsum   = (float*)((char*)&bt[0][0] + 4560);      // 4 f

  const int t = threadIdx.x, w = t >> 6, l = t & 63;
  const int col = l & 15, q = l >> 4;
  const int R0 = blockIdx.x * 256;
  const float4* zf4 = (const float4*)zf;
  const float4* cb4 = (const float4*)cb;

  // prologue: stage chunk 0 (16KB) into buf 0; load full cc
  #pragma unroll
  for (int i = 0; i < 4; ++i) {
    int s0 = i * 256 + w * 64;            // wave-uniform 16B-slot base
    gl_lds16(cbs + (size_t)(s0 + l) * 8, &bt[0][(size_t)s0 * 8]);
  }
  #pragma unroll
  for (int i = 0; i < 2; ++i)
    ((float4*)cc_l)[i * 256 + t] = ((const float4*)cc)[i * 256 + t];

  // A-fragments (r12-validated): lane holds A[m=l&15][k=q*8+j]; per tile
  // row = R0 + tile*64 + 16w + col; seg s covers dims s*32 + q*8 + j.
  s16x8 az1[4][2], az2[4][2];   // [tile][seg]: bf16(-2z) and exact residual
  #pragma unroll
  for (int tile = 0; tile < 4; ++tile) {
    int row = R0 + tile * 64 + 16 * w + col;
    const float4* zr = zf4 + (size_t)row * 16;
    #pragma unroll
    for (int s = 0; s < 2; ++s) {
      float4 u0 = zr[s * 8 + q * 2];
      float4 u1 = zr[s * 8 + q * 2 + 1];
      float m2[8] = {-2.f*u0.x, -2.f*u0.y, -2.f*u0.z, -2.f*u0.w,
                     -2.f*u1.x, -2.f*u1.y, -2.f*u1.z, -2.f*u1.w};
      #pragma unroll
      for (int j = 0; j < 8; ++j) {
        unsigned short h1 = f2bf(m2[j]);
        unsigned short h2 = f2bf(m2[j] - bf2f(h1));
        az1[tile][s][j] = (short)h1;
        az2[tile][s][j] = (short)h2;
      }
    }
  }

  unsigned p1[4][4], p2[4][4];   // packed (trunc dist | pid): best / second
  #pragma unroll
  for (int tile = 0; tile < 4; ++tile)
    #pragma unroll
    for (int r = 0; r < 4; ++r) { p1[tile][r] = 0xFFFFFFFFu; p2[tile][r] = 0xFFFFFFFFu; }

  __syncthreads();   // drains prologue stage + cc_l writes

  int cur = 0;
  for (int chunk = 0; chunk < 32; ++chunk) {
    if (chunk + 1 < 32) {            // prefetch next chunk into buf^1
      const unsigned short* src = cbs + (size_t)(chunk + 1) * 8192;
      unsigned short* dst = &bt[cur ^ 1][0];
      #pragma unroll
      for (int i = 0; i < 4; ++i) {
        int s0 = i * 256 + w * 64;
        gl_lds16(src + (size_t)(s0 + l) * 8, dst + (size_t)s0 * 8);
      }
    }
    const unsigned short* bb = &bt[cur][l * 8];
    const float* ccc = &cc_l[chunk * 64 + col];
    #pragma unroll
    for (int ct = 0; ct < 4; ++ct) {
      float nh = DIST_OFF + ccc[ct * 16];
      const unsigned short* base = bb + ct * 512;
      s16x8 b0 = *(const s16x8*)(base + 0 * 2048);   // c1 dims 0-31
      s16x8 b1 = *(const s16x8*)(base + 1 * 2048);   // c1 dims 32-63
      s16x8 b2 = *(const s16x8*)(base + 2 * 2048);   // c2 dims 0-31
      s16x8 b3 = *(const s16x8*)(base + 3 * 2048);   // c2 dims 32-63
      unsigned pid = (unsigned)(chunk * 4 + ct);     // 7 bits, ascending codes
      #pragma unroll
      for (int tile = 0; tile < 4; ++tile) {
        f32x4 acc; acc[0] = nh; acc[1] = nh; acc[2] = nh; acc[3] = nh;
        acc = __builtin_amdgcn_mfma_f32_16x16x32_bf16(az1[tile][0], b0, acc, 0, 0, 0);
        acc = __builtin_amdgcn_mfma_f32_16x16x32_bf16(az1[tile][1], b1, acc, 0, 0, 0);
        acc = __builtin_amdgcn_mfma_f32_16x16x32_bf16(az1[tile][0], b2, acc, 0, 0, 0);
        acc = __builtin_amdgcn_mfma_f32_16x16x32_bf16(az1[tile][1], b3, acc, 0, 0, 0);
        acc = __builtin_amdgcn_mfma_f32_16x16x32_bf16(az2[tile][0], b0, acc, 0, 0, 0);
        acc = __builtin_amdgcn_mfma_f32_16x16x32_bf16(az2[tile][1], b1, acc, 0, 0, 0);
        #pragma unroll
        for (int r = 0; r < 4; ++r) {   // packed (best, second): 4 int ops
          unsigned pd = (__float_as_uint(acc[r]) & 0xFFFFFF80u) | pid;
          unsigned mx = p1[tile][r] > pd ? p1[tile][r] : pd;
          p2[tile][r] = p2[tile][r] < mx ? p2[tile][r] : mx;
          p1[tile][r] = p1[tile][r] < pd ? p1[tile][r] : pd;
        }
      }
    }
    __syncthreads();   // readers done with cur; prefetch landed in cur^1
    cur ^= 1;
  }

  // ---- phase 2: unpack + merge across the 16 lanes of each row group ----
  if (t == 0) *nf = 0;
  __syncthreads();     // bt dead; arena live from here
  #pragma unroll
  for (int tile = 0; tile < 4; ++tile) {
    #pragma unroll
    for (int r = 0; r < 4; ++r) {
      float a   = __uint_as_float(p1[tile][r] & 0xFFFFFF80u);
      int   ia  = (int)(p1[tile][r] & 127u) * 16 + col;   // code = pid*16 + col
      float b2v = __uint_as_float(p2[tile][r] & 0xFFFFFF80u);
      #pragma unroll
      for (int m = 1; m < 16; m <<= 1) {
        float oa = __shfl_xor(a, m, 64);
        int   oi = __shfl_xor(ia, m, 64);
        float ob = __shfl_xor(b2v, m, 64);
        float hv = fmaxf(a, oa);
        b2v = fminf(fminf(b2v, ob), hv);
        bool take = (oa < a) || (oa == a && oi < ia);
        a = take ? oa : a; ia = take ? oi : ia;
      }
      if (col == 0) {   // C/D: col=l&15, row=(l>>4)*4+r [m89, validated]
        int rl = tile * 64 + 16 * w + q * 4 + r;
        idx_l[rl] = ia;
        if (b2v - a < MARGIN_T) {
          int p = atomicAdd(nf, 1);
          flg[p] = rl;
        }
      }
    }
  }
  __syncthreads();

  // ---- phase 3: exact fp32 rescore of flagged rows (validated inner chain) ----
  int count = *nf;
  for (int itb = 0; itb * 8 < count; ++itb) {
    if (itb) __syncthreads();
    if (t < 8) {
      int ii = itb * 8 + t;
      rows_s[t] = flg[ii < count ? ii : count - 1];  // tail dup: benign rewrite
    }
    __syncthreads();
    if (t < 128) {
      int r = t >> 4, dq = t & 15;
      *(float4*)&zl[r][dq * 4] = zf4[(size_t)(R0 + rows_s[r]) * 16 + dq];
    }
    __syncthreads();
    if (t < 8) {                          // zz: sequential-d np chain
      float s = 0.f;
      for (int d = 0; d < 64; ++d) { float v = zl[t][d]; s += v * v; }
      zz_l[t] = s;
    }
    __syncthreads();

    float bv[8]; int bi[8];
    #pragma unroll
    for (int r = 0; r < 8; ++r) { bv[r] = 3.402823466e38f; bi[r] = 0; }
    #pragma unroll 1
    for (int o = 0; o < 8; ++o) {         // thread's codes ascending: o*256+t
      int c = o * 256 + t;
      const float4* cr = cb4 + (size_t)c * 16;
      float a[8];
      #pragma unroll
      for (int r = 0; r < 8; ++r) a[r] = 0.f;
      #pragma unroll
      for (int dq = 0; dq < 16; ++dq) {
        float4 cv = cr[dq];
        #pragma unroll
        for (int r = 0; r < 8; ++r) {
          float4 z4 = *(const float4*)&zl[r][dq * 4];
          a[r] += z4.x * cv.x;
          a[r] += z4.y * cv.y;
          a[r] += z4.z * cv.z;
          a[r] += z4.w * cv.w;
        }
      }
      float ccv = cc_l[c];
      #pragma unroll
      for (int r = 0; r < 8; ++r) {
        float t0 = zz_l[r] - 2.0f * a[r];
        float dist = t0 + ccv;
        if (dist < bv[r]) { bv[r] = dist; bi[r] = c; }
      }
    }
    #pragma unroll
    for (int r = 0; r < 8; ++r) {
      float v = bv[r]; int idx = bi[r];
      #pragma unroll
      for (int m = 1; m < 64; m <<= 1) {
        float ov = __shfl_xor(v, m, 64); int oi = __shfl_xor(idx, m, 64);
        if (ov < v || (ov == v && oi < idx)) { v = ov; idx = oi; }
      }
      if (l == 0) { rv[w][r] = v; ri[w][r] = idx; }
    }
    __syncthreads();
    if (t < 8) {
      float fv = rv[0][t]; int fi = ri[0][t];
      #pragma unroll
      for (int k = 1; k < 4; ++k) {
        if (rv[k][t] < fv || (rv[k][t] == fv && ri[k][t] < fi)) { fv = rv[k][t]; fi = ri[k][t]; }
      }
      idx_l[rows_s[t]] = fi;
    }
  }
  __syncthreads();

  // ---- phase 4: epilogue for this block's 256 rows ----
  float4* out4 = (float4*)out;
  float lsum = 0.f;
  #pragma unroll
  for (int i = 0; i < 16; ++i) {
    int f = i * 256 + t;
    int row = f >> 4, dq = f & 15;
    int k = idx_l[row];
    float4 qv = cb4[(size_t)k * 16 + dq];
    float4 zv = zf4[(size_t)(R0 + row) * 16 + dq];
    float dx = qv.x - zv.x, dy = qv.y - zv.y, dz = qv.z - zv.z, dw = qv.w - zv.w;
    float4 st; st.x = zv.x + dx; st.y = zv.y + dy; st.z = zv.z + dz; st.w = zv.w + dw;
    out4[(size_t)(R0 + row) * 16 + dq] = st;
    lsum += dx * dx; lsum += dy * dy; lsum += dz * dz; lsum += dw * dw;
  }
  out[IDX_OFF + R0 + t] = (float)idx_l[t];
  #pragma unroll
  for (int m = 1; m < 64; m <<= 1) lsum += __shfl_xor(lsum, m, 64);
  if (l == 0) wsum[w] = lsum;
  __syncthreads();
  if (t == 0) atomicAdd(loss, wsum[0] + wsum[1] + wsum[2] + wsum[3]);
}

__global__ void vq_finalize(const float* __restrict__ loss, float* __restrict__ out) {
  out[LOSS_OFF] = loss[0] * (1.f / 8388608.f);
}

extern "C" void kernel_launch(void* const* d_in, const int* in_sizes, int n_in,
                              void* d_out, int out_size, void* d_ws, size_t ws_size,
                              hipStream_t stream) {
  const float* z  = (const float*)d_in[0];
  const float* cb = (const float*)d_in[1];
  float* out = (float*)d_out;
  float* loss = (float*)((char*)d_ws + WS_LOSS);
  float* cc   = (float*)((char*)d_ws + WS_CC);
  unsigned short* cbs = (unsigned short*)((char*)d_ws + WS_CBS);

  vq_prep<<<1024, 256, 0, stream>>>(cb, cc, cbs, loss);
  VQQuantizer_30064771072206_kernel<<<512, 256, 0, stream>>>(z, cb, cbs, cc, loss, out);
  vq_finalize<<<1, 1, 0, stream>>>(loss, out);
}

// Round 7
// 240.735 us; speedup vs baseline: 2.8663x; 1.6043x over previous
//
#include <hip/hip_runtime.h>

typedef short s16x8 __attribute__((ext_vector_type(8)));  // 8 bf16
typedef float f32x4 __attribute__((ext_vector_type(4)));  // 16x16 MFMA acc

#define CODES_ELEMS 8388608   // 16*1024*512
#define N_ROWS      131072    // 16*1024*8
#define IDX_OFF     CODES_ELEMS
#define LOSS_OFF    (CODES_ELEMS + N_ROWS)

// d_ws: [0,4) loss acc; [64,8256) cc[2048];
// [8448,532736) cbs bf16-split tiled codebook [chunk32][seg4][ct4][lane64][8]
//   seg 0,1 = c1 dims 0-31/32-63; seg 2,3 = c2 exact residual dims 0-31/32-63
#define WS_LOSS 0
#define WS_CC   64
#define WS_CBS  8448
// validated r13-r16 (absmax 0 x4): packed-min + margin + offset constants
#define MARGIN_T 0.0625f
#define DIST_OFF 512.0f

__device__ __forceinline__ float bf2f(unsigned short h) { return __uint_as_float(((unsigned)h) << 16); }
__device__ __forceinline__ unsigned short f2bf(float f) {   // RNE
  unsigned u = __float_as_uint(f);
  u += 0x7fffu + ((u >> 16) & 1u);
  return (unsigned short)(u >> 16);
}
// async global->LDS, 16B/lane; dest = wave-uniform base + lane*16
__device__ __forceinline__ void gl_lds16(const void* g, void* l) {
  __builtin_amdgcn_global_load_lds(
      (__attribute__((address_space(1))) void*)(g),
      (__attribute__((address_space(3))) void*)(l), 16, 0, 0);
}

// Prep (validated r16): bf16-split codebook into 16x16x32 B-fragment layout
// (chunk 64 codes / ct-width 4) + cc[k] butterfly.
__global__ __launch_bounds__(256) void vq_prep(const float* __restrict__ cb,
                                               float* __restrict__ cc,
                                               unsigned short* __restrict__ cbs,
                                               float* __restrict__ loss) {
  int t = threadIdx.x;
  if (blockIdx.x == 0 && t == 0) loss[0] = 0.f;
  int e = blockIdx.x * 256 + t;   // 1024*256 = 2048 codes * 128 K-elems
  int k = e >> 7, K = e & 127;
  int s = K >> 5, rem = K & 31, q = rem >> 3, j = rem & 7;
  int d = (s < 2) ? K : (K - 64);
  float c = cb[k * 64 + d];
  unsigned short c1 = f2bf(c);
  unsigned short val = (s < 2) ? c1 : f2bf(c - bf2f(c1));  // exact residual split
  int chunk = k >> 6, ct = (k >> 4) & 3, n = k & 15;
  cbs[(((size_t)(chunk * 4 + s) * 4 + ct) * 64 + (q * 16 + n)) * 8 + j] = val;
  float sq = c * c;
  #pragma unroll
  for (int m = 1; m < 64; m <<= 1) sq += __shfl_xor(sq, m, 64);
  if ((t & 63) == 0) cc[k] = sq;
}

// Mega-kernel r17 = r16 (absmax 0) with the tail's register-pressure bombs
// defused: r16 compiled at 256 VGPR + scratch spill because the fused kernel's
// budget = peak program point, and the tail's full unrolls (phase 4: 32 hoisted
// float4 loads = 128 regs; phase 3: 16 hoisted cv = 64 regs) were the peak —
// NOT the K-loop (r12-proven at 100 VGPR). Caps: phase 4 unroll 2, phase 3
// dq-loop unroll 4. K-loop/phases otherwise byte-identical to r16.
__global__ __launch_bounds__(256) void VQQuantizer_30064771072206_kernel(
    const float* __restrict__ zf, const float* __restrict__ cb,
    const unsigned short* __restrict__ cbs, const float* __restrict__ cc,
    float* __restrict__ loss, float* __restrict__ out)
{
  __shared__ __align__(16) unsigned short bt[2][8192];   // 2 x 16KB: [seg4][ct4][lane64][8]
  __shared__ __align__(16) float cc_l[2048];
  // ---- tail arena aliased onto bt (only touched after the K-loop) ----
  int*   idx_l  = (int*)&bt[0][0];                        // 256 ints  [0,1024)
  int*   flg    = (int*)((char*)&bt[0][0] + 1024);        // 256 ints  [1024,2048)
  int*   nf     = (int*)((char*)&bt[0][0] + 2048);        // [2048,2052)
  float (*zl)[68] = (float(*)[68])((char*)&bt[0][0] + 2064);  // 8*68 f
  float* zz_l   = (float*)((char*)&bt[0][0] + 4240);      // 8 f
  int*   rows_s = (int*)((char*)&bt[0][0] + 4272);        // 8 i
  float (*rv)[8] = (float(*)[8])((char*)&bt[0][0] + 4304); // 4x8 f
  int   (*ri)[8] = (int(*)[8])((char*)&bt[0][0] + 4432);   // 4x8 i
  float* wsum   = (float*)((char*)&bt[0][0] + 4560);      // 4 f

  const int t = threadIdx.x, w = t >> 6, l = t & 63;
  const int col = l & 15, q = l >> 4;
  const int R0 = blockIdx.x * 256;
  const float4* zf4 = (const float4*)zf;
  const float4* cb4 = (const float4*)cb;

  // prologue: stage chunk 0 (16KB) into buf 0; load full cc
  #pragma unroll
  for (int i = 0; i < 4; ++i) {
    int s0 = i * 256 + w * 64;            // wave-uniform 16B-slot base
    gl_lds16(cbs + (size_t)(s0 + l) * 8, &bt[0][(size_t)s0 * 8]);
  }
  #pragma unroll
  for (int i = 0; i < 2; ++i)
    ((float4*)cc_l)[i * 256 + t] = ((const float4*)cc)[i * 256 + t];

  // A-fragments (r12-validated): lane holds A[m=l&15][k=q*8+j]; per tile
  // row = R0 + tile*64 + 16w + col; seg s covers dims s*32 + q*8 + j.
  s16x8 az1[4][2], az2[4][2];   // [tile][seg]: bf16(-2z) and exact residual
  #pragma unroll
  for (int tile = 0; tile < 4; ++tile) {
    int row = R0 + tile * 64 + 16 * w + col;
    const float4* zr = zf4 + (size_t)row * 16;
    #pragma unroll
    for (int s = 0; s < 2; ++s) {
      float4 u0 = zr[s * 8 + q * 2];
      float4 u1 = zr[s * 8 + q * 2 + 1];
      float m2[8] = {-2.f*u0.x, -2.f*u0.y, -2.f*u0.z, -2.f*u0.w,
                     -2.f*u1.x, -2.f*u1.y, -2.f*u1.z, -2.f*u1.w};
      #pragma unroll
      for (int j = 0; j < 8; ++j) {
        unsigned short h1 = f2bf(m2[j]);
        unsigned short h2 = f2bf(m2[j] - bf2f(h1));
        az1[tile][s][j] = (short)h1;
        az2[tile][s][j] = (short)h2;
      }
    }
  }

  unsigned p1[4][4], p2[4][4];   // packed (trunc dist | pid): best / second
  #pragma unroll
  for (int tile = 0; tile < 4; ++tile)
    #pragma unroll
    for (int r = 0; r < 4; ++r) { p1[tile][r] = 0xFFFFFFFFu; p2[tile][r] = 0xFFFFFFFFu; }

  __syncthreads();   // drains prologue stage + cc_l writes

  int cur = 0;
  for (int chunk = 0; chunk < 32; ++chunk) {
    if (chunk + 1 < 32) {            // prefetch next chunk into buf^1
      const unsigned short* src = cbs + (size_t)(chunk + 1) * 8192;
      unsigned short* dst = &bt[cur ^ 1][0];
      #pragma unroll
      for (int i = 0; i < 4; ++i) {
        int s0 = i * 256 + w * 64;
        gl_lds16(src + (size_t)(s0 + l) * 8, dst + (size_t)s0 * 8);
      }
    }
    const unsigned short* bb = &bt[cur][l * 8];
    const float* ccc = &cc_l[chunk * 64 + col];
    #pragma unroll
    for (int ct = 0; ct < 4; ++ct) {
      float nh = DIST_OFF + ccc[ct * 16];
      const unsigned short* base = bb + ct * 512;
      s16x8 b0 = *(const s16x8*)(base + 0 * 2048);   // c1 dims 0-31
      s16x8 b1 = *(const s16x8*)(base + 1 * 2048);   // c1 dims 32-63
      s16x8 b2 = *(const s16x8*)(base + 2 * 2048);   // c2 dims 0-31
      s16x8 b3 = *(const s16x8*)(base + 3 * 2048);   // c2 dims 32-63
      unsigned pid = (unsigned)(chunk * 4 + ct);     // 7 bits, ascending codes
      #pragma unroll
      for (int tile = 0; tile < 4; ++tile) {
        f32x4 acc; acc[0] = nh; acc[1] = nh; acc[2] = nh; acc[3] = nh;
        acc = __builtin_amdgcn_mfma_f32_16x16x32_bf16(az1[tile][0], b0, acc, 0, 0, 0);
        acc = __builtin_amdgcn_mfma_f32_16x16x32_bf16(az1[tile][1], b1, acc, 0, 0, 0);
        acc = __builtin_amdgcn_mfma_f32_16x16x32_bf16(az1[tile][0], b2, acc, 0, 0, 0);
        acc = __builtin_amdgcn_mfma_f32_16x16x32_bf16(az1[tile][1], b3, acc, 0, 0, 0);
        acc = __builtin_amdgcn_mfma_f32_16x16x32_bf16(az2[tile][0], b0, acc, 0, 0, 0);
        acc = __builtin_amdgcn_mfma_f32_16x16x32_bf16(az2[tile][1], b1, acc, 0, 0, 0);
        #pragma unroll
        for (int r = 0; r < 4; ++r) {   // packed (best, second): 4 int ops
          unsigned pd = (__float_as_uint(acc[r]) & 0xFFFFFF80u) | pid;
          unsigned mx = p1[tile][r] > pd ? p1[tile][r] : pd;
          p2[tile][r] = p2[tile][r] < mx ? p2[tile][r] : mx;
          p1[tile][r] = p1[tile][r] < pd ? p1[tile][r] : pd;
        }
      }
    }
    __syncthreads();   // readers done with cur; prefetch landed in cur^1
    cur ^= 1;
  }

  // ---- phase 2: unpack + merge across the 16 lanes of each row group ----
  if (t == 0) *nf = 0;
  __syncthreads();     // bt dead; arena live from here
  #pragma unroll
  for (int tile = 0; tile < 4; ++tile) {
    #pragma unroll
    for (int r = 0; r < 4; ++r) {
      float a   = __uint_as_float(p1[tile][r] & 0xFFFFFF80u);
      int   ia  = (int)(p1[tile][r] & 127u) * 16 + col;   // code = pid*16 + col
      float b2v = __uint_as_float(p2[tile][r] & 0xFFFFFF80u);
      #pragma unroll
      for (int m = 1; m < 16; m <<= 1) {
        float oa = __shfl_xor(a, m, 64);
        int   oi = __shfl_xor(ia, m, 64);
        float ob = __shfl_xor(b2v, m, 64);
        float hv = fmaxf(a, oa);
        b2v = fminf(fminf(b2v, ob), hv);
        bool take = (oa < a) || (oa == a && oi < ia);
        a = take ? oa : a; ia = take ? oi : ia;
      }
      if (col == 0) {   // C/D: col=l&15, row=(l>>4)*4+r [m89, validated]
        int rl = tile * 64 + 16 * w + q * 4 + r;
        idx_l[rl] = ia;
        if (b2v - a < MARGIN_T) {
          int p = atomicAdd(nf, 1);
          flg[p] = rl;
        }
      }
    }
  }
  __syncthreads();

  // ---- phase 3: exact fp32 rescore of flagged rows (validated inner chain;
  //      dq-loop unroll capped at 4 to keep register pressure below K-loop) ----
  int count = *nf;
  for (int itb = 0; itb * 8 < count; ++itb) {
    if (itb) __syncthreads();
    if (t < 8) {
      int ii = itb * 8 + t;
      rows_s[t] = flg[ii < count ? ii : count - 1];  // tail dup: benign rewrite
    }
    __syncthreads();
    if (t < 128) {
      int r = t >> 4, dq = t & 15;
      *(float4*)&zl[r][dq * 4] = zf4[(size_t)(R0 + rows_s[r]) * 16 + dq];
    }
    __syncthreads();
    if (t < 8) {                          // zz: sequential-d np chain
      float s = 0.f;
      for (int d = 0; d < 64; ++d) { float v = zl[t][d]; s += v * v; }
      zz_l[t] = s;
    }
    __syncthreads();

    float bv[8]; int bi[8];
    #pragma unroll
    for (int r = 0; r < 8; ++r) { bv[r] = 3.402823466e38f; bi[r] = 0; }
    #pragma unroll 1
    for (int o = 0; o < 8; ++o) {         // thread's codes ascending: o*256+t
      int c = o * 256 + t;
      const float4* cr = cb4 + (size_t)c * 16;
      float a[8];
      #pragma unroll
      for (int r = 0; r < 8; ++r) a[r] = 0.f;
      #pragma unroll 4                    // cap hoisted cv regs (r16: 16 -> 64 VGPR)
      for (int dq = 0; dq < 16; ++dq) {
        float4 cv = cr[dq];
        #pragma unroll
        for (int r = 0; r < 8; ++r) {
          float4 z4 = *(const float4*)&zl[r][dq * 4];
          a[r] += z4.x * cv.x;
          a[r] += z4.y * cv.y;
          a[r] += z4.z * cv.z;
          a[r] += z4.w * cv.w;
        }
      }
      float ccv = cc_l[c];
      #pragma unroll
      for (int r = 0; r < 8; ++r) {
        float t0 = zz_l[r] - 2.0f * a[r];
        float dist = t0 + ccv;
        if (dist < bv[r]) { bv[r] = dist; bi[r] = c; }
      }
    }
    #pragma unroll
    for (int r = 0; r < 8; ++r) {
      float v = bv[r]; int idx = bi[r];
      #pragma unroll
      for (int m = 1; m < 64; m <<= 1) {
        float ov = __shfl_xor(v, m, 64); int oi = __shfl_xor(idx, m, 64);
        if (ov < v || (ov == v && oi < idx)) { v = ov; idx = oi; }
      }
      if (l == 0) { rv[w][r] = v; ri[w][r] = idx; }
    }
    __syncthreads();
    if (t < 8) {
      float fv = rv[0][t]; int fi = ri[0][t];
      #pragma unroll
      for (int k = 1; k < 4; ++k) {
        if (rv[k][t] < fv || (rv[k][t] == fv && ri[k][t] < fi)) { fv = rv[k][t]; fi = ri[k][t]; }
      }
      idx_l[rows_s[t]] = fi;
    }
  }
  __syncthreads();

  // ---- phase 4: epilogue for this block's 256 rows (unroll capped: r16's
  //      full unroll hoisted 32 float4 loads = 128 VGPR -> whole-kernel spill) ----
  float4* out4 = (float4*)out;
  float lsum = 0.f;
  #pragma unroll 2
  for (int i = 0; i < 16; ++i) {
    int f = i * 256 + t;
    int row = f >> 4, dq = f & 15;
    int k = idx_l[row];
    float4 qv = cb4[(size_t)k * 16 + dq];
    float4 zv = zf4[(size_t)(R0 + row) * 16 + dq];
    float dx = qv.x - zv.x, dy = qv.y - zv.y, dz = qv.z - zv.z, dw = qv.w - zv.w;
    float4 st; st.x = zv.x + dx; st.y = zv.y + dy; st.z = zv.z + dz; st.w = zv.w + dw;
    out4[(size_t)(R0 + row) * 16 + dq] = st;
    lsum += dx * dx; lsum += dy * dy; lsum += dz * dz; lsum += dw * dw;
  }
  out[IDX_OFF + R0 + t] = (float)idx_l[t];
  #pragma unroll
  for (int m = 1; m < 64; m <<= 1) lsum += __shfl_xor(lsum, m, 64);
  if (l == 0) wsum[w] = lsum;
  __syncthreads();
  if (t == 0) atomicAdd(loss, wsum[0] + wsum[1] + wsum[2] + wsum[3]);
}

__global__ void vq_finalize(const float* __restrict__ loss, float* __restrict__ out) {
  out[LOSS_OFF] = loss[0] * (1.f / 8388608.f);
}

extern "C" void kernel_launch(void* const* d_in, const int* in_sizes, int n_in,
                              void* d_out, int out_size, void* d_ws, size_t ws_size,
                              hipStream_t stream) {
  const float* z  = (const float*)d_in[0];
  const float* cb = (const float*)d_in[1];
  float* out = (float*)d_out;
  float* loss = (float*)((char*)d_ws + WS_LOSS);
  float* cc   = (float*)((char*)d_ws + WS_CC);
  unsigned short* cbs = (unsigned short*)((char*)d_ws + WS_CBS);

  vq_prep<<<1024, 256, 0, stream>>>(cb, cc, cbs, loss);
  VQQuantizer_30064771072206_kernel<<<512, 256, 0, stream>>>(z, cb, cbs, cc, loss, out);
  vq_finalize<<<1, 1, 0, stream>>>(loss, out);
}